// Round 4
// baseline (604.603 us; speedup 1.0000x reference)
//
#include <hip/hip_runtime.h>
#include <math.h>

typedef unsigned short ushort_t;
typedef __attribute__((ext_vector_type(8))) short short8;
typedef __attribute__((ext_vector_type(4))) float f32x4;

#define MFMA16(a, b, c) __builtin_amdgcn_mfma_f32_16x16x32_bf16((a), (b), (c), 0, 0, 0)

static __device__ __forceinline__ ushort_t f2bf(float f) {
  unsigned int u = __float_as_uint(f);
  u = u + 0x7FFFu + ((u >> 16) & 1u);  // RTNE
  return (ushort_t)(u >> 16);
}
static __device__ __forceinline__ float bf2f(ushort_t s) {
  return __uint_as_float(((unsigned int)s) << 16);
}

// async global->LDS, 16B per lane. l_uniform: wave-uniform LDS base (lane*16 implicit).
static __device__ __forceinline__ void stage16(const ushort_t* g_perlane, char* l_uniform, int lane) {
#if __has_builtin(__builtin_amdgcn_global_load_lds)
  __builtin_amdgcn_global_load_lds((const __attribute__((address_space(1))) void*)g_perlane,
                                   (__attribute__((address_space(3))) void*)l_uniform, 16, 0, 0);
#else
  *(uint4*)(l_uniform + lane * 16) = *(const uint4*)g_perlane;
#endif
}

// ---------------- RMSNorm fp32 in -> bf16 out ----------------
__global__ __launch_bounds__(256) void rmsnorm_k(const float* __restrict__ x,
                                                 const float* __restrict__ g,
                                                 ushort_t* __restrict__ o) {
  const int r = blockIdx.x, t = threadIdx.x;
  const float4 xv = ((const float4*)(x + (size_t)r * 1024))[t];
  float ss = xv.x * xv.x + xv.y * xv.y + xv.z * xv.z + xv.w * xv.w;
#pragma unroll
  for (int m = 32; m >= 1; m >>= 1) ss += __shfl_xor(ss, m);
  __shared__ float wp[4];
  if ((t & 63) == 0) wp[t >> 6] = ss;
  __syncthreads();
  const float inv = rsqrtf((wp[0] + wp[1] + wp[2] + wp[3]) * (1.f / 1024.f) + 1e-5f);
  const float4 gv = ((const float4*)g)[t];
  ushort4 ov = {f2bf(xv.x * inv * gv.x), f2bf(xv.y * inv * gv.y),
                f2bf(xv.z * inv * gv.z), f2bf(xv.w * inv * gv.w)};
  *(ushort4*)(o + (size_t)r * 1024 + t * 4) = ov;
}

// ---------------- transpose + cast: fp32 [R][C] -> bf16 [C][R] ----------------
__global__ __launch_bounds__(256) void transpose_cast_k(const float* __restrict__ in,
                                                        ushort_t* __restrict__ out,
                                                        int R, int C) {
  __shared__ ushort_t Ts[64][72];
  const int t = threadIdx.x;
  const int c0 = blockIdx.x * 64, r0 = blockIdx.y * 64;
  const int lr = t >> 4, lc = (t & 15) * 4;
#pragma unroll
  for (int i = 0; i < 4; ++i) {
    const float4 v = *(const float4*)&in[(size_t)(r0 + lr + i * 16) * C + c0 + lc];
    Ts[lr + i * 16][lc + 0] = f2bf(v.x);
    Ts[lr + i * 16][lc + 1] = f2bf(v.y);
    Ts[lr + i * 16][lc + 2] = f2bf(v.z);
    Ts[lr + i * 16][lc + 3] = f2bf(v.w);
  }
  __syncthreads();
  const int rr = (t & 15) * 4;
#pragma unroll
  for (int i = 0; i < 4; ++i) {
    const int cc = (t >> 4) + i * 16;
    ushort4 o = {Ts[rr + 0][cc], Ts[rr + 1][cc], Ts[rr + 2][cc], Ts[rr + 3][cc]};
    *(ushort4*)&out[(size_t)(c0 + cc) * R + r0 + rr] = o;
  }
}

// ---------------- RoPE in-place on bf16, ld=3072; scale folded (Q: 0.125) ----------------
__global__ __launch_bounds__(256) void rope_k(ushort_t* __restrict__ buf, float scale) {
  const int idx = blockIdx.x * 256 + threadIdx.x;  // 4096*16*8
  const int row = idx >> 7, rem = idx & 127;
  const int head = rem >> 3, gq = rem & 7;
  const int i0 = gq * 4;
  const int s = row & 2047;
  ushort_t* p = buf + (size_t)row * 3072 + head * 64 + i0 * 2;
  uint4 v = *(uint4*)p;
  ushort_t* e = (ushort_t*)&v;
#pragma unroll
  for (int k = 0; k < 4; ++k) {
    const float ang = (float)s * expf(-(float)(i0 + k) * 0.28782313662425572f);  // ln(1e4)/32
    float sn, cs;
    sincosf(ang, &sn, &cs);
    const float x1 = bf2f(e[2 * k]), x2 = bf2f(e[2 * k + 1]);
    e[2 * k] = f2bf((x1 * cs - x2 * sn) * scale);
    e[2 * k + 1] = f2bf((x2 * cs + x1 * sn) * scale);
  }
  *(uint4*)p = v;
}

// ---------------- MFMA GEMM: A[M][K] bf16, Bt[N][K] bf16 ----------------
// MODE 0: C=bf16(A@B). MODE 1: C=fp32(A@B + R). MODE 2: C=bf16(silu(A@B1)*(A@B2)).
// 128x128 tile, BK=32, 4 waves (2x2 of 64x64), 16x16x32 MFMA.
// LDS: fragment-major 16B slots, slot = g*128 + row (g = k-octet 0..3).
//   -> MFMA fragment reads are 16 consecutive slots (conflict-free).
//   -> staged via global_load_lds with pre-permuted per-lane global source.
template <int MODE>
__global__ __launch_bounds__(256) void gemm_k(const ushort_t* __restrict__ A,
                                              const ushort_t* __restrict__ Bt,
                                              const ushort_t* __restrict__ Bt2,
                                              const float* __restrict__ R,
                                              void* __restrict__ C,
                                              int N, int K) {
  __shared__ uint4 smem[(MODE == 2 ? 24576 : 16384) / 16];
  char* sm = (char*)smem;
  const int t = threadIdx.x, lane = t & 63, w = t >> 6;
  const int g = lane >> 4, li = lane & 15;
  const int wr = w >> 1, wc = w & 1;
  const int n0 = blockIdx.x * 128, m0 = blockIdx.y * 128;
  const int wb = t & 192;  // w*64, wave-uniform
  // pre-permuted global slot decomposition for the two staging calls
  const int r0s = t & 127, g0s = (t >> 7) << 3;            // call 0: slot = t
  const int r1s = r0s, g1s = g0s + 16;                      // call 1: slot = 256+t  (g += 2)
  f32x4 acc[4][4] = {};
  f32x4 acc2[4][4] = {};
  const int nkt = K >> 5;
  for (int kt = 0; kt < nkt; ++kt) {
    __syncthreads();
    {
      const int k0 = kt << 5;
      stage16(A + (size_t)(m0 + r0s) * K + k0 + g0s, sm + ((0 + wb) << 4), lane);
      stage16(A + (size_t)(m0 + r1s) * K + k0 + g1s, sm + ((256 + wb) << 4), lane);
      stage16(Bt + (size_t)(n0 + r0s) * K + k0 + g0s, sm + 8192 + ((0 + wb) << 4), lane);
      stage16(Bt + (size_t)(n0 + r1s) * K + k0 + g1s, sm + 8192 + ((256 + wb) << 4), lane);
      if (MODE == 2) {
        stage16(Bt2 + (size_t)(n0 + r0s) * K + k0 + g0s, sm + 16384 + ((0 + wb) << 4), lane);
        stage16(Bt2 + (size_t)(n0 + r1s) * K + k0 + g1s, sm + 16384 + ((256 + wb) << 4), lane);
      }
    }
    __syncthreads();
    short8 af[4], bfr[4], bfr2[4];
#pragma unroll
    for (int mi = 0; mi < 4; ++mi)
      af[mi] = *(const short8*)(sm + ((g * 128 + wr * 64 + mi * 16 + li) << 4));
#pragma unroll
    for (int ni = 0; ni < 4; ++ni)
      bfr[ni] = *(const short8*)(sm + 8192 + ((g * 128 + wc * 64 + ni * 16 + li) << 4));
    if (MODE == 2) {
#pragma unroll
      for (int ni = 0; ni < 4; ++ni)
        bfr2[ni] = *(const short8*)(sm + 16384 + ((g * 128 + wc * 64 + ni * 16 + li) << 4));
    }
#pragma unroll
    for (int mi = 0; mi < 4; ++mi)
#pragma unroll
      for (int ni = 0; ni < 4; ++ni) {
        acc[mi][ni] = MFMA16(af[mi], bfr[ni], acc[mi][ni]);
        if (MODE == 2) acc2[mi][ni] = MFMA16(af[mi], bfr2[ni], acc2[mi][ni]);
      }
  }
#pragma unroll
  for (int mi = 0; mi < 4; ++mi)
#pragma unroll
    for (int ni = 0; ni < 4; ++ni)
#pragma unroll
      for (int r = 0; r < 4; ++r) {
        const int row = m0 + wr * 64 + mi * 16 + g * 4 + r;
        const int col = n0 + wc * 64 + ni * 16 + li;
        float v = acc[mi][ni][r];
        if (MODE == 2) {
          const float a2 = acc2[mi][ni][r];
          v = v / (1.f + __expf(-v)) * a2;
        }
        if (MODE == 1)
          ((float*)C)[(size_t)row * N + col] = v + R[(size_t)row * N + col];
        else
          ((ushort_t*)C)[(size_t)row * N + col] = f2bf(v);
      }
}

// ---------------- MFMA flash attention (causal), bf16 QKV packed ld=3072 ----------------
// grid (S/64=32, B*H=32), 256 thr = 4 waves, wave w owns q-rows [q0+16w, +16).
// LDS: Ks [64key][64dh] swz | Vt [64dh][64key] swz | Ps per-wave [16q][64key] swz.
__global__ __launch_bounds__(256) void attn_k(const ushort_t* __restrict__ qkv,
                                              ushort_t* __restrict__ ctx) {
  __shared__ uint4 smemv[24576 / 16];
  char* sm = (char*)smemv;
  const int qt = blockIdx.x, bh = blockIdx.y;
  const int b = bh >> 4, h = bh & 15;
  const int t = threadIdx.x, lane = t & 63, w = t >> 6;
  const int g = lane >> 4, li = lane & 15;
  const int rowb = b * 2048;
  const size_t qbase = (size_t)rowb * 3072 + h * 64;
  const int q0 = qt * 64;

  short8 qa[2];
  {
    const int qrow = q0 + w * 16 + li;
    qa[0] = *(const short8*)(qkv + qbase + (size_t)qrow * 3072 + 8 * g);
    qa[1] = *(const short8*)(qkv + qbase + (size_t)qrow * 3072 + 32 + 8 * g);
  }
  f32x4 acc[4] = {};
  float mr[4], lr[4];
#pragma unroll
  for (int r = 0; r < 4; ++r) { mr[r] = -INFINITY; lr[r] = 0.f; }

  const int srow = t >> 2, sc = t & 3;
  for (int kt = 0; kt <= qt; ++kt) {
    __syncthreads();
    {  // stage K rows (full 128B per row: 16 elems/thread) and V^T (scatter), both swizzled
      const ushort_t* kp = qkv + qbase + 1024 + (size_t)(kt * 64 + srow) * 3072 + sc * 16;
      const uint4 k0 = *(const uint4*)kp, k1 = *(const uint4*)(kp + 8);
      *(uint4*)(sm + srow * 128 + ((sc * 32) ^ ((srow & 7) << 4))) = k0;
      *(uint4*)(sm + srow * 128 + ((sc * 32 + 16) ^ ((srow & 7) << 4))) = k1;
      const ushort_t* vp = qkv + qbase + 2048 + (size_t)(kt * 64 + srow) * 3072 + sc * 16;
      ushort_t tmp[16];
      *(uint4*)tmp = *(const uint4*)vp;
      *(uint4*)(tmp + 8) = *(const uint4*)(vp + 8);
#pragma unroll
      for (int e = 0; e < 16; ++e) {
        const int dh = sc * 16 + e;
        *(ushort_t*)(sm + 8192 + dh * 128 + ((2 * srow) ^ ((dh & 7) << 4))) = tmp[e];
      }
    }
    __syncthreads();
    // QK^T: s[nt] covers keys nt*16+li, q-rows g*4+r (wave-local)
    f32x4 s[4];
#pragma unroll
    for (int nt = 0; nt < 4; ++nt) {
      const int key = nt * 16 + li;
      const short8 kb0 = *(const short8*)(sm + key * 128 + ((16 * g) ^ ((key & 7) << 4)));
      const short8 kb1 = *(const short8*)(sm + key * 128 + ((64 + 16 * g) ^ ((key & 7) << 4)));
      f32x4 z = {0.f, 0.f, 0.f, 0.f};
      z = MFMA16(qa[0], kb0, z);
      z = MFMA16(qa[1], kb1, z);
      s[nt] = z;
    }
    if (kt == qt) {  // causal mask on diagonal tile
#pragma unroll
      for (int nt = 0; nt < 4; ++nt)
#pragma unroll
        for (int r = 0; r < 4; ++r) {
          const int key = kt * 64 + nt * 16 + li;
          const int qq = q0 + w * 16 + g * 4 + r;
          if (key > qq) s[nt][r] = -INFINITY;
        }
    }
    // online softmax (reduce over 16-lane groups: masks 1,2,4,8)
#pragma unroll
    for (int r = 0; r < 4; ++r) {
      float tm = fmaxf(fmaxf(s[0][r], s[1][r]), fmaxf(s[2][r], s[3][r]));
#pragma unroll
      for (int m = 8; m >= 1; m >>= 1) tm = fmaxf(tm, __shfl_xor(tm, m));
      const float nm = fmaxf(mr[r], tm);
      const float rs = __expf(mr[r] - nm);
      mr[r] = nm;
      float ps = 0.f;
#pragma unroll
      for (int nt = 0; nt < 4; ++nt) {
        const float p = __expf(s[nt][r] - nm);
        s[nt][r] = p;
        ps += p;
      }
#pragma unroll
      for (int m = 8; m >= 1; m >>= 1) ps += __shfl_xor(ps, m);
      lr[r] = lr[r] * rs + ps;
#pragma unroll
      for (int dt = 0; dt < 4; ++dt) acc[dt][r] *= rs;
    }
    // write P (bf16) to wave-private LDS, swizzled
#pragma unroll
    for (int nt = 0; nt < 4; ++nt)
#pragma unroll
      for (int r = 0; r < 4; ++r) {
        const int q = g * 4 + r;
        const int colb = 2 * (nt * 16 + li);
        *(ushort_t*)(sm + 16384 + w * 2048 + q * 128 + (colb ^ ((q & 7) << 4))) = f2bf(s[nt][r]);
      }
    // PV
    short8 pa[2];
    pa[0] = *(const short8*)(sm + 16384 + w * 2048 + li * 128 + ((16 * g) ^ ((li & 7) << 4)));
    pa[1] = *(const short8*)(sm + 16384 + w * 2048 + li * 128 + ((64 + 16 * g) ^ ((li & 7) << 4)));
#pragma unroll
    for (int dt = 0; dt < 4; ++dt) {
      const int dh = dt * 16 + li;
      const short8 vb0 = *(const short8*)(sm + 8192 + dh * 128 + ((16 * g) ^ ((dh & 7) << 4)));
      const short8 vb1 = *(const short8*)(sm + 8192 + dh * 128 + ((64 + 16 * g) ^ ((dh & 7) << 4)));
      acc[dt] = MFMA16(pa[0], vb0, acc[dt]);
      acc[dt] = MFMA16(pa[1], vb1, acc[dt]);
    }
  }
#pragma unroll
  for (int dt = 0; dt < 4; ++dt)
#pragma unroll
    for (int r = 0; r < 4; ++r) {
      const int row = rowb + q0 + w * 16 + g * 4 + r;
      const int col = h * 64 + dt * 16 + li;
      ctx[(size_t)row * 1024 + col] = f2bf(acc[dt][r] / lr[r]);
    }
}

extern "C" void kernel_launch(void* const* d_in, const int* in_sizes, int n_in,
                              void* d_out, int out_size, void* d_ws, size_t ws_size,
                              hipStream_t stream) {
  const float* x = (const float*)d_in[0];
  const float* Wq = (const float*)d_in[1];
  const float* Wk = (const float*)d_in[2];
  const float* Wv = (const float*)d_in[3];
  const float* Wo = (const float*)d_in[4];
  const float* g1 = (const float*)d_in[5];
  const float* g2 = (const float*)d_in[6];
  const float* W1 = (const float*)d_in[7];
  const float* W2 = (const float*)d_in[8];
  const float* W3 = (const float*)d_in[9];
  float* out = (float*)d_out;

  char* wsb = (char*)d_ws;
  ushort_t* hb = (ushort_t*)(wsb);                         // 8 MiB
  ushort_t* qkv = (ushort_t*)(wsb + (8u << 20));           // 24 MiB
  ushort_t* ctx = (ushort_t*)(wsb + (32u << 20));          // 8 MiB
  ushort_t* gbuf = (ushort_t*)(wsb + (8u << 20));          // 32 MiB, overlays dead qkv+ctx
  ushort_t* wqkvT = (ushort_t*)(wsb + (40u << 20));        // 6 MiB
  ushort_t* woT = (ushort_t*)(wsb + (46u << 20));          // 2 MiB
  ushort_t* w13T = (ushort_t*)(wsb + (48u << 20));         // 16 MiB
  ushort_t* w2T = (ushort_t*)(wsb + (64u << 20));          // 8 MiB

  // weight transpose+cast to bf16 [N][K]
  transpose_cast_k<<<dim3(16, 16), 256, 0, stream>>>(Wq, wqkvT, 1024, 1024);
  transpose_cast_k<<<dim3(16, 16), 256, 0, stream>>>(Wk, wqkvT + 1024 * 1024, 1024, 1024);
  transpose_cast_k<<<dim3(16, 16), 256, 0, stream>>>(Wv, wqkvT + 2 * 1024 * 1024, 1024, 1024);
  transpose_cast_k<<<dim3(16, 16), 256, 0, stream>>>(Wo, woT, 1024, 1024);
  transpose_cast_k<<<dim3(64, 16), 256, 0, stream>>>(W1, w13T, 1024, 4096);
  transpose_cast_k<<<dim3(64, 16), 256, 0, stream>>>(W3, w13T + 4096 * 1024, 1024, 4096);
  transpose_cast_k<<<dim3(16, 64), 256, 0, stream>>>(W2, w2T, 4096, 1024);

  // 1. h = rmsnorm(x, g1) -> bf16
  rmsnorm_k<<<4096, 256, 0, stream>>>(x, g1, hb);
  // 2. qkv = h @ [Wq|Wk|Wv]
  gemm_k<0><<<dim3(24, 32), 256, 0, stream>>>(hb, wqkvT, nullptr, nullptr, qkv, 3072, 1024);
  // 3. RoPE (Q gets 1/sqrt(dh) folded in)
  rope_k<<<2048, 256, 0, stream>>>(qkv, 0.125f);
  rope_k<<<2048, 256, 0, stream>>>(qkv + 1024, 1.0f);
  // 4. ctx = causal flash attention
  attn_k<<<dim3(32, 32), 256, 0, stream>>>(qkv, ctx);
  // 5. out1 = x + ctx @ Wo  (fp32)
  gemm_k<1><<<dim3(8, 32), 256, 0, stream>>>(ctx, woT, nullptr, x, out, 1024, 1024);
  // 6. h2 = rmsnorm(out1, g2) -> bf16
  rmsnorm_k<<<4096, 256, 0, stream>>>(out, g2, hb);
  // 7. gbuf = silu(h2@W1) * (h2@W3)
  gemm_k<2><<<dim3(32, 32), 256, 0, stream>>>(hb, w13T, w13T + 4096 * 1024, nullptr, gbuf, 4096, 1024);
  // 8. out = out1 + gbuf @ W2
  gemm_k<1><<<dim3(8, 32), 256, 0, stream>>>(gbuf, w2T, nullptr, out, out, 1024, 4096);
}

// Round 5
// 530.639 us; speedup vs baseline: 1.1394x; 1.1394x over previous
//
#include <hip/hip_runtime.h>
#include <math.h>

typedef unsigned short ushort_t;
typedef __attribute__((ext_vector_type(8))) short short8;
typedef __attribute__((ext_vector_type(4))) float f32x4;

#define MFMA16(a, b, c) __builtin_amdgcn_mfma_f32_16x16x32_bf16((a), (b), (c), 0, 0, 0)

static __device__ __forceinline__ ushort_t f2bf(float f) {
  unsigned int u = __float_as_uint(f);
  u = u + 0x7FFFu + ((u >> 16) & 1u);  // RTNE
  return (ushort_t)(u >> 16);
}
static __device__ __forceinline__ float bf2f(ushort_t s) {
  return __uint_as_float(((unsigned int)s) << 16);
}

// async global->LDS, 16B per lane. l_uniform: wave-uniform LDS base (lane*16 implicit).
static __device__ __forceinline__ void stage16(const ushort_t* g_perlane, char* l_uniform, int lane) {
#if __has_builtin(__builtin_amdgcn_global_load_lds)
  __builtin_amdgcn_global_load_lds((const __attribute__((address_space(1))) void*)g_perlane,
                                   (__attribute__((address_space(3))) void*)l_uniform, 16, 0, 0);
#else
  *(uint4*)(l_uniform + lane * 16) = *(const uint4*)g_perlane;
#endif
}

// ---------------- RMSNorm fp32 in -> bf16 out ----------------
__global__ __launch_bounds__(256) void rmsnorm_k(const float* __restrict__ x,
                                                 const float* __restrict__ g,
                                                 ushort_t* __restrict__ o) {
  const int r = blockIdx.x, t = threadIdx.x;
  const float4 xv = ((const float4*)(x + (size_t)r * 1024))[t];
  float ss = xv.x * xv.x + xv.y * xv.y + xv.z * xv.z + xv.w * xv.w;
#pragma unroll
  for (int m = 32; m >= 1; m >>= 1) ss += __shfl_xor(ss, m);
  __shared__ float wp[4];
  if ((t & 63) == 0) wp[t >> 6] = ss;
  __syncthreads();
  const float inv = rsqrtf((wp[0] + wp[1] + wp[2] + wp[3]) * (1.f / 1024.f) + 1e-5f);
  const float4 gv = ((const float4*)g)[t];
  ushort4 ov = {f2bf(xv.x * inv * gv.x), f2bf(xv.y * inv * gv.y),
                f2bf(xv.z * inv * gv.z), f2bf(xv.w * inv * gv.w)};
  *(ushort4*)(o + (size_t)r * 1024 + t * 4) = ov;
}

// ---------------- transpose + cast: fp32 [R][C] -> bf16 [C][R] ----------------
__global__ __launch_bounds__(256) void transpose_cast_k(const float* __restrict__ in,
                                                        ushort_t* __restrict__ out,
                                                        int R, int C) {
  __shared__ ushort_t Ts[64][72];
  const int t = threadIdx.x;
  const int c0 = blockIdx.x * 64, r0 = blockIdx.y * 64;
  const int lr = t >> 4, lc = (t & 15) * 4;
#pragma unroll
  for (int i = 0; i < 4; ++i) {
    const float4 v = *(const float4*)&in[(size_t)(r0 + lr + i * 16) * C + c0 + lc];
    Ts[lr + i * 16][lc + 0] = f2bf(v.x);
    Ts[lr + i * 16][lc + 1] = f2bf(v.y);
    Ts[lr + i * 16][lc + 2] = f2bf(v.z);
    Ts[lr + i * 16][lc + 3] = f2bf(v.w);
  }
  __syncthreads();
  const int rr = (t & 15) * 4;
#pragma unroll
  for (int i = 0; i < 4; ++i) {
    const int cc = (t >> 4) + i * 16;
    ushort4 o = {Ts[rr + 0][cc], Ts[rr + 1][cc], Ts[rr + 2][cc], Ts[rr + 3][cc]};
    *(ushort4*)&out[(size_t)(c0 + cc) * R + r0 + rr] = o;
  }
}

// ---------------- RoPE in-place on bf16, ld=3072; scale folded (Q: 0.125) ----------------
__global__ __launch_bounds__(256) void rope_k(ushort_t* __restrict__ buf, float scale) {
  const int idx = blockIdx.x * 256 + threadIdx.x;  // 4096*16*8
  const int row = idx >> 7, rem = idx & 127;
  const int head = rem >> 3, gq = rem & 7;
  const int i0 = gq * 4;
  const int s = row & 2047;
  ushort_t* p = buf + (size_t)row * 3072 + head * 64 + i0 * 2;
  uint4 v = *(uint4*)p;
  ushort_t* e = (ushort_t*)&v;
#pragma unroll
  for (int k = 0; k < 4; ++k) {
    const float ang = (float)s * expf(-(float)(i0 + k) * 0.28782313662425572f);  // ln(1e4)/32
    float sn, cs;
    sincosf(ang, &sn, &cs);
    const float x1 = bf2f(e[2 * k]), x2 = bf2f(e[2 * k + 1]);
    e[2 * k] = f2bf((x1 * cs - x2 * sn) * scale);
    e[2 * k + 1] = f2bf((x2 * cs + x1 * sn) * scale);
  }
  *(uint4*)p = v;
}

// ---------------- MFMA GEMM: A[M][K] bf16, Bt[N][K] bf16 ----------------
// MODE 0: C=bf16(A@B). MODE 1: C=fp32(A@B + R). MODE 2: C=bf16(silu(A@B1)*(A@B2)).
// 128x128 tile, BK=32, 4 waves (2x2 of 64x64), 16x16x32 MFMA.
// LDS: fragment-major 16B slots (slot = g*128 + row), DOUBLE-BUFFERED.
// 2-phase pipeline: issue next K-tile's global_load_lds BEFORE current tile's
// ds_read+MFMA; single __syncthreads per K-step (its vmcnt drain lands after
// the compute has covered most of the HBM latency).
template <int MODE>
__global__ __launch_bounds__(256) void gemm_k(const ushort_t* __restrict__ A,
                                              const ushort_t* __restrict__ Bt,
                                              const ushort_t* __restrict__ Bt2,
                                              const float* __restrict__ R,
                                              void* __restrict__ C,
                                              int N, int K) {
  __shared__ uint4 smem[(MODE == 2 ? 49152 : 32768) / 16];
  char* sm = (char*)smem;
  const int t = threadIdx.x, lane = t & 63, w = t >> 6;
  const int g = lane >> 4, li = lane & 15;
  const int wr = w >> 1, wc = w & 1;
  const int n0 = blockIdx.x * 128, m0 = blockIdx.y * 128;
  const int wb = t & 192;  // w*64, wave-uniform
  // pre-permuted global decomposition: call0 stages slot=t, call1 slot=256+t
  const int r0s = t & 127, g0s = (t >> 7) << 3;
  const size_t rowA = (size_t)(m0 + r0s) * K;
  const size_t rowB = (size_t)(n0 + r0s) * K;
  f32x4 acc[4][4] = {};
  f32x4 acc2[4][4] = {};
  const int nkt = K >> 5;

  auto stage_all = [&](int buf, int kt) {
    const int k0 = (kt << 5) + g0s;
    char* dA = sm + buf * 8192;
    char* dB = sm + 16384 + buf * 8192;
    stage16(A + rowA + k0, dA + (wb << 4), lane);
    stage16(A + rowA + k0 + 16, dA + ((256 + wb) << 4), lane);
    stage16(Bt + rowB + k0, dB + (wb << 4), lane);
    stage16(Bt + rowB + k0 + 16, dB + ((256 + wb) << 4), lane);
    if (MODE == 2) {
      char* dC = sm + 32768 + buf * 8192;
      stage16(Bt2 + rowB + k0, dC + (wb << 4), lane);
      stage16(Bt2 + rowB + k0 + 16, dC + ((256 + wb) << 4), lane);
    }
  };

  stage_all(0, 0);
  __syncthreads();
  int cur = 0;
  for (int kt = 0; kt < nkt; ++kt) {
    if (kt + 1 < nkt) stage_all(cur ^ 1, kt + 1);  // prefetch overlaps compute below
    const char* smA = sm + cur * 8192;
    const char* smB = sm + 16384 + cur * 8192;
    short8 af[4], bfr[4], bfr2[4];
#pragma unroll
    for (int mi = 0; mi < 4; ++mi)
      af[mi] = *(const short8*)(smA + ((g * 128 + wr * 64 + mi * 16 + li) << 4));
#pragma unroll
    for (int ni = 0; ni < 4; ++ni)
      bfr[ni] = *(const short8*)(smB + ((g * 128 + wc * 64 + ni * 16 + li) << 4));
    if (MODE == 2) {
      const char* smB2 = sm + 32768 + cur * 8192;
#pragma unroll
      for (int ni = 0; ni < 4; ++ni)
        bfr2[ni] = *(const short8*)(smB2 + ((g * 128 + wc * 64 + ni * 16 + li) << 4));
    }
#pragma unroll
    for (int mi = 0; mi < 4; ++mi)
#pragma unroll
      for (int ni = 0; ni < 4; ++ni) {
        acc[mi][ni] = MFMA16(af[mi], bfr[ni], acc[mi][ni]);
        if (MODE == 2) acc2[mi][ni] = MFMA16(af[mi], bfr2[ni], acc2[mi][ni]);
      }
    __syncthreads();  // protects buf cur (re-staged next iter) + drains prefetch
    cur ^= 1;
  }
#pragma unroll
  for (int mi = 0; mi < 4; ++mi)
#pragma unroll
    for (int ni = 0; ni < 4; ++ni)
#pragma unroll
      for (int r = 0; r < 4; ++r) {
        const int row = m0 + wr * 64 + mi * 16 + g * 4 + r;
        const int col = n0 + wc * 64 + ni * 16 + li;
        float v = acc[mi][ni][r];
        if (MODE == 2) {
          const float a2 = acc2[mi][ni][r];
          v = v / (1.f + __expf(-v)) * a2;
        }
        if (MODE == 1)
          ((float*)C)[(size_t)row * N + col] = v + R[(size_t)row * N + col];
        else
          ((ushort_t*)C)[(size_t)row * N + col] = f2bf(v);
      }
}

// ---------------- MFMA flash attention (causal), bf16 QKV packed ld=3072 ----------------
// grid (S/64=32, B*H=32), 256 thr = 4 waves, wave w owns q-rows [q0+16w, +16).
// LDS: Ks [64key][64dh] swz | Vt [64dh][64key] swz | Ps per-wave [16q][64key] swz.
__global__ __launch_bounds__(256) void attn_k(const ushort_t* __restrict__ qkv,
                                              ushort_t* __restrict__ ctx) {
  __shared__ uint4 smemv[24576 / 16];
  char* sm = (char*)smemv;
  const int qt = blockIdx.x, bh = blockIdx.y;
  const int b = bh >> 4, h = bh & 15;
  const int t = threadIdx.x, lane = t & 63, w = t >> 6;
  const int g = lane >> 4, li = lane & 15;
  const int rowb = b * 2048;
  const size_t qbase = (size_t)rowb * 3072 + h * 64;
  const int q0 = qt * 64;

  short8 qa[2];
  {
    const int qrow = q0 + w * 16 + li;
    qa[0] = *(const short8*)(qkv + qbase + (size_t)qrow * 3072 + 8 * g);
    qa[1] = *(const short8*)(qkv + qbase + (size_t)qrow * 3072 + 32 + 8 * g);
  }
  f32x4 acc[4] = {};
  float mr[4], lr[4];
#pragma unroll
  for (int r = 0; r < 4; ++r) { mr[r] = -INFINITY; lr[r] = 0.f; }

  const int srow = t >> 2, sc = t & 3;
  for (int kt = 0; kt <= qt; ++kt) {
    __syncthreads();
    {  // stage K rows (full 128B per row: 16 elems/thread) and V^T (scatter), both swizzled
      const ushort_t* kp = qkv + qbase + 1024 + (size_t)(kt * 64 + srow) * 3072 + sc * 16;
      const uint4 k0 = *(const uint4*)kp, k1 = *(const uint4*)(kp + 8);
      *(uint4*)(sm + srow * 128 + ((sc * 32) ^ ((srow & 7) << 4))) = k0;
      *(uint4*)(sm + srow * 128 + ((sc * 32 + 16) ^ ((srow & 7) << 4))) = k1;
      const ushort_t* vp = qkv + qbase + 2048 + (size_t)(kt * 64 + srow) * 3072 + sc * 16;
      ushort_t tmp[16];
      *(uint4*)tmp = *(const uint4*)vp;
      *(uint4*)(tmp + 8) = *(const uint4*)(vp + 8);
#pragma unroll
      for (int e = 0; e < 16; ++e) {
        const int dh = sc * 16 + e;
        *(ushort_t*)(sm + 8192 + dh * 128 + ((2 * srow) ^ ((dh & 7) << 4))) = tmp[e];
      }
    }
    __syncthreads();
    // QK^T: s[nt] covers keys nt*16+li, q-rows g*4+r (wave-local)
    f32x4 s[4];
#pragma unroll
    for (int nt = 0; nt < 4; ++nt) {
      const int key = nt * 16 + li;
      const short8 kb0 = *(const short8*)(sm + key * 128 + ((16 * g) ^ ((key & 7) << 4)));
      const short8 kb1 = *(const short8*)(sm + key * 128 + ((64 + 16 * g) ^ ((key & 7) << 4)));
      f32x4 z = {0.f, 0.f, 0.f, 0.f};
      z = MFMA16(qa[0], kb0, z);
      z = MFMA16(qa[1], kb1, z);
      s[nt] = z;
    }
    if (kt == qt) {  // causal mask on diagonal tile
#pragma unroll
      for (int nt = 0; nt < 4; ++nt)
#pragma unroll
        for (int r = 0; r < 4; ++r) {
          const int key = kt * 64 + nt * 16 + li;
          const int qq = q0 + w * 16 + g * 4 + r;
          if (key > qq) s[nt][r] = -INFINITY;
        }
    }
    // online softmax (reduce over 16-lane groups: masks 1,2,4,8)
#pragma unroll
    for (int r = 0; r < 4; ++r) {
      float tm = fmaxf(fmaxf(s[0][r], s[1][r]), fmaxf(s[2][r], s[3][r]));
#pragma unroll
      for (int m = 8; m >= 1; m >>= 1) tm = fmaxf(tm, __shfl_xor(tm, m));
      const float nm = fmaxf(mr[r], tm);
      const float rs = __expf(mr[r] - nm);
      mr[r] = nm;
      float ps = 0.f;
#pragma unroll
      for (int nt = 0; nt < 4; ++nt) {
        const float p = __expf(s[nt][r] - nm);
        s[nt][r] = p;
        ps += p;
      }
#pragma unroll
      for (int m = 8; m >= 1; m >>= 1) ps += __shfl_xor(ps, m);
      lr[r] = lr[r] * rs + ps;
#pragma unroll
      for (int dt = 0; dt < 4; ++dt) acc[dt][r] *= rs;
    }
    // write P (bf16) to wave-private LDS, swizzled
#pragma unroll
    for (int nt = 0; nt < 4; ++nt)
#pragma unroll
      for (int r = 0; r < 4; ++r) {
        const int q = g * 4 + r;
        const int colb = 2 * (nt * 16 + li);
        *(ushort_t*)(sm + 16384 + w * 2048 + q * 128 + (colb ^ ((q & 7) << 4))) = f2bf(s[nt][r]);
      }
    // PV
    short8 pa[2];
    pa[0] = *(const short8*)(sm + 16384 + w * 2048 + li * 128 + ((16 * g) ^ ((li & 7) << 4)));
    pa[1] = *(const short8*)(sm + 16384 + w * 2048 + li * 128 + ((64 + 16 * g) ^ ((li & 7) << 4)));
#pragma unroll
    for (int dt = 0; dt < 4; ++dt) {
      const int dh = dt * 16 + li;
      const short8 vb0 = *(const short8*)(sm + 8192 + dh * 128 + ((16 * g) ^ ((dh & 7) << 4)));
      const short8 vb1 = *(const short8*)(sm + 8192 + dh * 128 + ((64 + 16 * g) ^ ((dh & 7) << 4)));
      acc[dt] = MFMA16(pa[0], vb0, acc[dt]);
      acc[dt] = MFMA16(pa[1], vb1, acc[dt]);
    }
  }
#pragma unroll
  for (int dt = 0; dt < 4; ++dt)
#pragma unroll
    for (int r = 0; r < 4; ++r) {
      const int row = rowb + q0 + w * 16 + g * 4 + r;
      const int col = h * 64 + dt * 16 + li;
      ctx[(size_t)row * 1024 + col] = f2bf(acc[dt][r] / lr[r]);
    }
}

extern "C" void kernel_launch(void* const* d_in, const int* in_sizes, int n_in,
                              void* d_out, int out_size, void* d_ws, size_t ws_size,
                              hipStream_t stream) {
  const float* x = (const float*)d_in[0];
  const float* Wq = (const float*)d_in[1];
  const float* Wk = (const float*)d_in[2];
  const float* Wv = (const float*)d_in[3];
  const float* Wo = (const float*)d_in[4];
  const float* g1 = (const float*)d_in[5];
  const float* g2 = (const float*)d_in[6];
  const float* W1 = (const float*)d_in[7];
  const float* W2 = (const float*)d_in[8];
  const float* W3 = (const float*)d_in[9];
  float* out = (float*)d_out;

  char* wsb = (char*)d_ws;
  ushort_t* hb = (ushort_t*)(wsb);                         // 8 MiB
  ushort_t* qkv = (ushort_t*)(wsb + (8u << 20));           // 24 MiB
  ushort_t* ctx = (ushort_t*)(wsb + (32u << 20));          // 8 MiB
  ushort_t* gbuf = (ushort_t*)(wsb + (8u << 20));          // 32 MiB, overlays dead qkv+ctx
  ushort_t* wqkvT = (ushort_t*)(wsb + (40u << 20));        // 6 MiB
  ushort_t* woT = (ushort_t*)(wsb + (46u << 20));          // 2 MiB
  ushort_t* w13T = (ushort_t*)(wsb + (48u << 20));         // 16 MiB
  ushort_t* w2T = (ushort_t*)(wsb + (64u << 20));          // 8 MiB

  // weight transpose+cast to bf16 [N][K]
  transpose_cast_k<<<dim3(16, 16), 256, 0, stream>>>(Wq, wqkvT, 1024, 1024);
  transpose_cast_k<<<dim3(16, 16), 256, 0, stream>>>(Wk, wqkvT + 1024 * 1024, 1024, 1024);
  transpose_cast_k<<<dim3(16, 16), 256, 0, stream>>>(Wv, wqkvT + 2 * 1024 * 1024, 1024, 1024);
  transpose_cast_k<<<dim3(16, 16), 256, 0, stream>>>(Wo, woT, 1024, 1024);
  transpose_cast_k<<<dim3(64, 16), 256, 0, stream>>>(W1, w13T, 1024, 4096);
  transpose_cast_k<<<dim3(64, 16), 256, 0, stream>>>(W3, w13T + 4096 * 1024, 1024, 4096);
  transpose_cast_k<<<dim3(16, 64), 256, 0, stream>>>(W2, w2T, 4096, 1024);

  // 1. h = rmsnorm(x, g1) -> bf16
  rmsnorm_k<<<4096, 256, 0, stream>>>(x, g1, hb);
  // 2. qkv = h @ [Wq|Wk|Wv]
  gemm_k<0><<<dim3(24, 32), 256, 0, stream>>>(hb, wqkvT, nullptr, nullptr, qkv, 3072, 1024);
  // 3. RoPE (Q gets 1/sqrt(dh) folded in)
  rope_k<<<2048, 256, 0, stream>>>(qkv, 0.125f);
  rope_k<<<2048, 256, 0, stream>>>(qkv + 1024, 1.0f);
  // 4. ctx = causal flash attention
  attn_k<<<dim3(32, 32), 256, 0, stream>>>(qkv, ctx);
  // 5. out1 = x + ctx @ Wo  (fp32)
  gemm_k<1><<<dim3(8, 32), 256, 0, stream>>>(ctx, woT, nullptr, x, out, 1024, 1024);
  // 6. h2 = rmsnorm(out1, g2) -> bf16
  rmsnorm_k<<<4096, 256, 0, stream>>>(out, g2, hb);
  // 7. gbuf = silu(h2@W1) * (h2@W3)
  gemm_k<2><<<dim3(32, 32), 256, 0, stream>>>(hb, w13T, w13T + 4096 * 1024, nullptr, gbuf, 4096, 1024);
  // 8. out = out1 + gbuf @ W2
  gemm_k<1><<<dim3(8, 32), 256, 0, stream>>>(gbuf, w2T, nullptr, out, out, 1024, 4096);
}